// Round 1
// baseline (1166.315 us; speedup 1.0000x reference)
//
#include <hip/hip_runtime.h>

#define BSZ 2
#define SEQ 2048
#define DMODEL 512
#define NH 8
#define HDIM 64
#define LROW 2047
#define RJS 2048
#define MAXLEN 1024
#define OUT_ELEMS (BSZ * SEQ * DMODEL)

typedef __bf16 bf16;
typedef bf16 bf16x8 __attribute__((ext_vector_type(8)));
typedef float f32x4 __attribute__((ext_vector_type(4)));

__device__ __forceinline__ f32x4 mfma16(bf16x8 a, bf16x8 b, f32x4 c) {
    return __builtin_amdgcn_mfma_f32_16x16x32_bf16(a, b, c, 0, 0, 0);
}
__device__ __forceinline__ void split2(float x, bf16 &h, bf16 &l) {
    h = (bf16)x;
    l = (bf16)(x - (float)h);
}

// ---------------- K0a: transpose + hi/lo split of Wq/Wk/Wv -> Wt[n][k] ----------------
__global__ __launch_bounds__(256) void prep_w(const float* __restrict__ Wq,
                                              const float* __restrict__ Wk,
                                              const float* __restrict__ Wv,
                                              bf16* __restrict__ wt_hi,
                                              bf16* __restrict__ wt_lo) {
    __shared__ float tile[64][65];
    const int wz = blockIdx.z;
    const float* W = (wz == 0) ? Wq : (wz == 1) ? Wk : Wv;
    bf16* oh = wt_hi + (size_t)wz * DMODEL * DMODEL;
    bf16* ol = wt_lo + (size_t)wz * DMODEL * DMODEL;
    const int k0 = blockIdx.x * 64;
    const int n0 = blockIdx.y * 64;
    const int tid = threadIdx.x;
    for (int e = tid; e < 64 * 64; e += 256) {
        int kk = e >> 6, nn = e & 63;
        tile[nn][kk] = W[(size_t)(k0 + kk) * DMODEL + n0 + nn];
    }
    __syncthreads();
    for (int e = tid; e < 64 * 64; e += 256) {
        int nn = e >> 6, kk = e & 63;
        float x = tile[nn][kk];
        bf16 h, l;
        split2(x, h, l);
        oh[(size_t)(n0 + nn) * DMODEL + k0 + kk] = h;
        ol[(size_t)(n0 + nn) * DMODEL + k0 + kk] = l;
    }
}

// ---------------- K0b: hi/lo split of Er -> [h][2048][64] (row 2047 zeroed) ----------------
__global__ __launch_bounds__(256) void prep_er(const float* __restrict__ Er,
                                               bf16* __restrict__ er_hi,
                                               bf16* __restrict__ er_lo) {
    const int idx = blockIdx.x * 256 + threadIdx.x;  // over NH*2048*64, exact grid
    const int h = idx >> 17;            // / (2048*64)
    const int rem = idx & 131071;
    const int j = rem >> 6, d = rem & 63;
    float x = (j < LROW) ? Er[((size_t)h * LROW + j) * HDIM + d] : 0.f;
    bf16 hh, ll;
    split2(x, hh, ll);
    er_hi[idx] = hh;
    er_lo[idx] = ll;
}

// ---------------- K1: q/k/v projections (split-bf16 MFMA), q/k -> [b,h,t,hd], v -> [b,h,hd,t] ----------------
__global__ __launch_bounds__(256) void proj_kernel(
    const float* __restrict__ qin, const float* __restrict__ kin, const float* __restrict__ vin,
    const bf16* __restrict__ wt_hi, const bf16* __restrict__ wt_lo,
    const float* __restrict__ bq, const float* __restrict__ bk, const float* __restrict__ bv,
    bf16* __restrict__ q_hi, bf16* __restrict__ q_lo,
    bf16* __restrict__ k_hi, bf16* __restrict__ k_lo,
    bf16* __restrict__ v_hi, bf16* __restrict__ v_lo) {
    const int wz = blockIdx.z;
    const float* X = (wz == 0) ? qin : (wz == 1) ? kin : vin;
    const float* bias = (wz == 0) ? bq : (wz == 1) ? bk : bv;
    const bf16* wh = wt_hi + (size_t)wz * DMODEL * DMODEL;
    const bf16* wl = wt_lo + (size_t)wz * DMODEL * DMODEL;
    const int tid = threadIdx.x, wv = tid >> 6, lane = tid & 63, g = lane >> 4, c = lane & 15;
    const int m0 = blockIdx.x * 64 + wv * 16;
    const int n0 = blockIdx.y * 64;
    const f32x4 z4 = {0.f, 0.f, 0.f, 0.f};
    f32x4 acc[4] = {z4, z4, z4, z4};
    for (int kk = 0; kk < DMODEL; kk += 32) {
        const float* xp = X + (size_t)(m0 + c) * DMODEL + kk + g * 8;
        float4 x0 = *(const float4*)xp;
        float4 x1 = *(const float4*)(xp + 4);
        float fv[8] = {x0.x, x0.y, x0.z, x0.w, x1.x, x1.y, x1.z, x1.w};
        bf16x8 ah, al;
#pragma unroll
        for (int i = 0; i < 8; i++) {
            bf16 hh, ll;
            split2(fv[i], hh, ll);
            ah[i] = hh;
            al[i] = ll;
        }
#pragma unroll
        for (int sub = 0; sub < 4; sub++) {
            const size_t wo = (size_t)(n0 + sub * 16 + c) * DMODEL + kk + g * 8;
            bf16x8 bh = *(const bf16x8*)(wh + wo);
            bf16x8 bl = *(const bf16x8*)(wl + wo);
            acc[sub] = mfma16(ah, bh, acc[sub]);
            acc[sub] = mfma16(ah, bl, acc[sub]);
            acc[sub] = mfma16(al, bh, acc[sub]);
        }
    }
#pragma unroll
    for (int sub = 0; sub < 4; sub++) {
        const int n = n0 + sub * 16 + c;
        const float bval = bias[n];
        const int hh = n >> 6, hd = n & 63;
#pragma unroll
        for (int r = 0; r < 4; r++) {
            const int m = m0 + g * 4 + r;
            const int bb = m >> 11, t = m & (SEQ - 1);
            float val = acc[sub][r] + bval;
            bf16 vh, vl;
            split2(val, vh, vl);
            if (wz == 2) {
                const size_t o = ((size_t)((bb * NH + hh) * HDIM + hd)) * SEQ + t;
                v_hi[o] = vh;
                v_lo[o] = vl;
            } else if (wz == 0) {
                const size_t o = ((size_t)((bb * NH + hh) * SEQ + t)) * HDIM + hd;
                q_hi[o] = vh;
                q_lo[o] = vl;
            } else {
                const size_t o = ((size_t)((bb * NH + hh) * SEQ + t)) * HDIM + hd;
                k_hi[o] = vh;
                k_lo[o] = vl;
            }
        }
    }
}

// ---------------- K2: R[b,h,t,j] = q[t] . Er[j]  (GEMM, fp16 output) ----------------
__global__ __launch_bounds__(256) void rel_kernel(
    const bf16* __restrict__ q_hi, const bf16* __restrict__ q_lo,
    const bf16* __restrict__ er_hi, const bf16* __restrict__ er_lo,
    _Float16* __restrict__ R) {
    const int bh = blockIdx.z;
    const int h = bh & 7;
    const int tid = threadIdx.x, wv = tid >> 6, lane = tid & 63, g = lane >> 4, c = lane & 15;
    const int t0 = blockIdx.x * 64 + wv * 16;
    const int j0 = blockIdx.y * 64;
    const bf16* qh = q_hi + (size_t)bh * SEQ * HDIM;
    const bf16* ql = q_lo + (size_t)bh * SEQ * HDIM;
    const bf16* eh = er_hi + (size_t)h * 2048 * HDIM;
    const bf16* el = er_lo + (size_t)h * 2048 * HDIM;
    const f32x4 z4 = {0.f, 0.f, 0.f, 0.f};
    f32x4 acc[4] = {z4, z4, z4, z4};
#pragma unroll
    for (int kc = 0; kc < 2; kc++) {
        const int kk = kc * 32 + g * 8;
        bf16x8 ah = *(const bf16x8*)(qh + (size_t)(t0 + c) * HDIM + kk);
        bf16x8 al = *(const bf16x8*)(ql + (size_t)(t0 + c) * HDIM + kk);
#pragma unroll
        for (int sub = 0; sub < 4; sub++) {
            bf16x8 bh_ = *(const bf16x8*)(eh + (size_t)(j0 + sub * 16 + c) * HDIM + kk);
            bf16x8 bl_ = *(const bf16x8*)(el + (size_t)(j0 + sub * 16 + c) * HDIM + kk);
            acc[sub] = mfma16(ah, bh_, acc[sub]);
            acc[sub] = mfma16(ah, bl_, acc[sub]);
            acc[sub] = mfma16(al, bh_, acc[sub]);
        }
    }
#pragma unroll
    for (int sub = 0; sub < 4; sub++)
#pragma unroll
        for (int r = 0; r < 4; r++) {
            const int t = t0 + g * 4 + r, j = j0 + sub * 16 + c;
            R[((size_t)bh * SEQ + t) * RJS + j] = (_Float16)acc[sub][r];
        }
}

// ---------------- K3: fused attention (two-pass online softmax, writes attn + out) ----------------
__global__ __launch_bounds__(256) void attn_kernel(
    const bf16* __restrict__ q_hi, const bf16* __restrict__ q_lo,
    const bf16* __restrict__ k_hi, const bf16* __restrict__ k_lo,
    const bf16* __restrict__ v_hi, const bf16* __restrict__ v_lo,
    const _Float16* __restrict__ R, const int* __restrict__ layer_p,
    float* __restrict__ out, float* __restrict__ attn) {
    __shared__ float att_s[4][16][36];  // per-wave, stride 36 breaks bank conflicts, keeps 16B align
    const int bh = blockIdx.y;
    const int b = bh >> 3, h = bh & 7;
    const int tid = threadIdx.x, wv = tid >> 6, lane = tid & 63, g = lane >> 4, c = lane & 15;
    const int t0 = blockIdx.x * 64 + wv * 16;
    const int layer = layer_p[0];
    const int strd = 1 << layer;
    const int dil = min(1 + (SEQ - 1) / strd, MAXLEN);

    const bf16* qh_p = q_hi + ((size_t)bh * SEQ + t0) * HDIM;
    const bf16* ql_p = q_lo + ((size_t)bh * SEQ + t0) * HDIM;
    const bf16* kh_p = k_hi + (size_t)bh * SEQ * HDIM;
    const bf16* kl_p = k_lo + (size_t)bh * SEQ * HDIM;
    const bf16* vh_p = v_hi + (size_t)bh * HDIM * SEQ;
    const bf16* vl_p = v_lo + (size_t)bh * HDIM * SEQ;
    const _Float16* Rp = R + (size_t)bh * SEQ * RJS;

    bf16x8 qh[2], ql[2];
#pragma unroll
    for (int kc = 0; kc < 2; kc++) {
        qh[kc] = *(const bf16x8*)(qh_p + c * HDIM + kc * 32 + g * 8);
        ql[kc] = *(const bf16x8*)(ql_p + c * HDIM + kc * 32 + g * 8);
    }

    auto tile_logits = [&](int s0) -> f32x4 {
        const f32x4 z = {0.f, 0.f, 0.f, 0.f};
        f32x4 aA = z, aB = z, aC = z;  // 3 independent chains for MFMA ILP
#pragma unroll
        for (int kc = 0; kc < 2; kc++) {
            const size_t ko = (size_t)(s0 + c) * HDIM + kc * 32 + g * 8;
            bf16x8 kh = *(const bf16x8*)(kh_p + ko);
            bf16x8 kl = *(const bf16x8*)(kl_p + ko);
            aA = mfma16(qh[kc], kh, aA);
            aB = mfma16(qh[kc], kl, aB);
            aC = mfma16(ql[kc], kh, aC);
        }
        f32x4 lg = aA + aB + aC;
#pragma unroll
        for (int r = 0; r < 4; r++) {
            const int t = t0 + g * 4 + r;
            const int dd = s0 + c - t;
            const int mm = dd >> layer;  // arithmetic shift; exact with divisibility mask
            const bool ok = ((dd & (strd - 1)) == 0) & (mm > -dil) & (mm < dil);
            float rel = 0.f;
            if (ok) rel = (float)Rp[(size_t)t * RJS + 1023 + mm];
            lg[r] = (lg[r] + rel) * 0.125f;  // 1/sqrt(64)
        }
        return lg;
    };

    float m_r[4], l_r[4];
#pragma unroll
    for (int r = 0; r < 4; r++) {
        m_r[r] = -1e30f;
        l_r[r] = 0.f;
    }

    // ---- pass 1: per-lane online max/sum (no cross-lane work inside the loop)
    for (int s0 = 0; s0 < SEQ; s0 += 16) {
        f32x4 lg = tile_logits(s0);
#pragma unroll
        for (int r = 0; r < 4; r++) {
            float x = lg[r];
            if (x > m_r[r]) {
                l_r[r] = l_r[r] * __expf(m_r[r] - x) + 1.f;
                m_r[r] = x;
            } else {
                l_r[r] += __expf(x - m_r[r]);
            }
        }
    }
    // merge across the 16 lanes of each column-group
#pragma unroll
    for (int mask = 1; mask < 16; mask <<= 1) {
#pragma unroll
        for (int r = 0; r < 4; r++) {
            float om = __shfl_xor(m_r[r], mask);
            float ol = __shfl_xor(l_r[r], mask);
            float mn = fmaxf(m_r[r], om);
            l_r[r] = l_r[r] * __expf(m_r[r] - mn) + ol * __expf(om - mn);
            m_r[r] = mn;
        }
    }
    float inv_l[4];
#pragma unroll
    for (int r = 0; r < 4; r++) inv_l[r] = 1.f / l_r[r];

    // ---- pass 2: recompute, write attn, accumulate PV
    const f32x4 z4 = {0.f, 0.f, 0.f, 0.f};
    f32x4 oacc[4] = {z4, z4, z4, z4};
    float* attn_p = attn + (size_t)bh * SEQ * SEQ;

    for (int s0 = 0; s0 < SEQ; s0 += 32) {
#pragma unroll
        for (int half = 0; half < 2; half++) {
            const int sb = s0 + half * 16;
            f32x4 lg = tile_logits(sb);
#pragma unroll
            for (int r = 0; r < 4; r++) {
                const int t = t0 + g * 4 + r;
                float av = __expf(lg[r] - m_r[r]) * inv_l[r];
                attn_p[(size_t)t * SEQ + sb + c] = av;
                att_s[wv][g * 4 + r][half * 16 + c] = av;
            }
        }
        // rebuild attn tile as MFMA A-fragments (bf16 hi/lo) via per-wave LDS
        bf16x8 pah, pal;
        {
            const float* ap = &att_s[wv][c][g * 8];
            float4 v0 = *(const float4*)ap;
            float4 v1 = *(const float4*)(ap + 4);
            float fv[8] = {v0.x, v0.y, v0.z, v0.w, v1.x, v1.y, v1.z, v1.w};
#pragma unroll
            for (int i = 0; i < 8; i++) {
                bf16 hh, ll;
                split2(fv[i], hh, ll);
                pah[i] = hh;
                pal[i] = ll;
            }
        }
#pragma unroll
        for (int sub = 0; sub < 4; sub++) {
            const size_t vo = (size_t)(sub * 16 + c) * SEQ + s0 + g * 8;
            bf16x8 vh = *(const bf16x8*)(vh_p + vo);
            bf16x8 vl = *(const bf16x8*)(vl_p + vo);
            oacc[sub] = mfma16(pah, vh, oacc[sub]);
            oacc[sub] = mfma16(pah, vl, oacc[sub]);
            oacc[sub] = mfma16(pal, vh, oacc[sub]);
        }
    }
#pragma unroll
    for (int sub = 0; sub < 4; sub++)
#pragma unroll
        for (int r = 0; r < 4; r++) {
            const int t = t0 + g * 4 + r;
            out[((size_t)b * SEQ + t) * DMODEL + h * HDIM + sub * 16 + c] = oacc[sub][r];
        }
}

extern "C" void kernel_launch(void* const* d_in, const int* in_sizes, int n_in,
                              void* d_out, int out_size, void* d_ws, size_t ws_size,
                              hipStream_t stream) {
    const float* query = (const float*)d_in[0];
    const float* key = (const float*)d_in[1];
    const float* value = (const float*)d_in[2];
    const float* Wq = (const float*)d_in[3];
    const float* bq = (const float*)d_in[4];
    const float* Wk = (const float*)d_in[5];
    const float* bk = (const float*)d_in[6];
    const float* Wv = (const float*)d_in[7];
    const float* bv = (const float*)d_in[8];
    const float* Er = (const float*)d_in[9];
    const int* layer = (const int*)d_in[10];

    char* ws = (char*)d_ws;
    size_t off = 0;
    bf16* wt_hi = (bf16*)(ws + off); off += (size_t)3 * DMODEL * DMODEL * 2;   // 1.5 MB
    bf16* wt_lo = (bf16*)(ws + off); off += (size_t)3 * DMODEL * DMODEL * 2;
    bf16* er_hi = (bf16*)(ws + off); off += (size_t)NH * 2048 * HDIM * 2;      // 2 MB
    bf16* er_lo = (bf16*)(ws + off); off += (size_t)NH * 2048 * HDIM * 2;
    bf16* q_hi = (bf16*)(ws + off); off += (size_t)BSZ * NH * SEQ * HDIM * 2;  // 4 MB each
    bf16* q_lo = (bf16*)(ws + off); off += (size_t)BSZ * NH * SEQ * HDIM * 2;
    bf16* k_hi = (bf16*)(ws + off); off += (size_t)BSZ * NH * SEQ * HDIM * 2;
    bf16* k_lo = (bf16*)(ws + off); off += (size_t)BSZ * NH * SEQ * HDIM * 2;
    bf16* v_hi = (bf16*)(ws + off); off += (size_t)BSZ * NH * SEQ * HDIM * 2;
    bf16* v_lo = (bf16*)(ws + off); off += (size_t)BSZ * NH * SEQ * HDIM * 2;
    _Float16* Rbuf = (_Float16*)(ws + off); off += (size_t)BSZ * NH * SEQ * RJS * 2;  // 134 MB

    float* out = (float*)d_out;
    float* attn = out + OUT_ELEMS;

    prep_w<<<dim3(8, 8, 3), 256, 0, stream>>>(Wq, Wk, Wv, wt_hi, wt_lo);
    prep_er<<<(NH * 2048 * HDIM) / 256, 256, 0, stream>>>(Er, er_hi, er_lo);
    proj_kernel<<<dim3(64, 8, 3), 256, 0, stream>>>(query, key, value, wt_hi, wt_lo,
                                                    bq, bk, bv,
                                                    q_hi, q_lo, k_hi, k_lo, v_hi, v_lo);
    rel_kernel<<<dim3(32, 32, 16), 256, 0, stream>>>(q_hi, q_lo, er_hi, er_lo, Rbuf);
    attn_kernel<<<dim3(32, 16), 256, 0, stream>>>(q_hi, q_lo, k_hi, k_lo, v_hi, v_lo,
                                                  Rbuf, layer, out, attn);
}

// Round 2
// 898.984 us; speedup vs baseline: 1.2974x; 1.2974x over previous
//
#include <hip/hip_runtime.h>

#define BSZ 2
#define SEQ 2048
#define DMODEL 512
#define NH 8
#define HDIM 64
#define LROW 2047
#define RJS 2048
#define MAXLEN 1024
#define OUT_ELEMS (BSZ * SEQ * DMODEL)

typedef __bf16 bf16;
typedef bf16 bf16x8 __attribute__((ext_vector_type(8)));
typedef float f32x4 __attribute__((ext_vector_type(4)));

__device__ __forceinline__ f32x4 mfma16(bf16x8 a, bf16x8 b, f32x4 c) {
    return __builtin_amdgcn_mfma_f32_16x16x32_bf16(a, b, c, 0, 0, 0);
}
__device__ __forceinline__ void split2(float x, bf16 &h, bf16 &l) {
    h = (bf16)x;
    l = (bf16)(x - (float)h);
}

// ---------------- K0a: transpose + hi/lo split of Wq/Wk/Wv -> Wt[n][k] ----------------
__global__ __launch_bounds__(256) void prep_w(const float* __restrict__ Wq,
                                              const float* __restrict__ Wk,
                                              const float* __restrict__ Wv,
                                              bf16* __restrict__ wt_hi,
                                              bf16* __restrict__ wt_lo) {
    __shared__ float tile[64][65];
    const int wz = blockIdx.z;
    const float* W = (wz == 0) ? Wq : (wz == 1) ? Wk : Wv;
    bf16* oh = wt_hi + (size_t)wz * DMODEL * DMODEL;
    bf16* ol = wt_lo + (size_t)wz * DMODEL * DMODEL;
    const int k0 = blockIdx.x * 64;
    const int n0 = blockIdx.y * 64;
    const int tid = threadIdx.x;
    for (int e = tid; e < 64 * 64; e += 256) {
        int kk = e >> 6, nn = e & 63;
        tile[nn][kk] = W[(size_t)(k0 + kk) * DMODEL + n0 + nn];
    }
    __syncthreads();
    for (int e = tid; e < 64 * 64; e += 256) {
        int nn = e >> 6, kk = e & 63;
        float x = tile[nn][kk];
        bf16 h, l;
        split2(x, h, l);
        oh[(size_t)(n0 + nn) * DMODEL + k0 + kk] = h;
        ol[(size_t)(n0 + nn) * DMODEL + k0 + kk] = l;
    }
}

// ---------------- K0b: hi/lo split of Er -> [h][2048][64] (row 2047 zeroed) ----------------
__global__ __launch_bounds__(256) void prep_er(const float* __restrict__ Er,
                                               bf16* __restrict__ er_hi,
                                               bf16* __restrict__ er_lo) {
    const int idx = blockIdx.x * 256 + threadIdx.x;
    const int h = idx >> 17;
    const int rem = idx & 131071;
    const int j = rem >> 6, d = rem & 63;
    float x = (j < LROW) ? Er[((size_t)h * LROW + j) * HDIM + d] : 0.f;
    bf16 hh, ll;
    split2(x, hh, ll);
    er_hi[idx] = hh;
    er_lo[idx] = ll;
}

// ---------------- K1: q/k/v projections. q/k -> [b,h,t,hd]; v via swapped operands -> [b,h,hd,t] ----------------
__global__ __launch_bounds__(256) void proj_kernel(
    const float* __restrict__ qin, const float* __restrict__ kin, const float* __restrict__ vin,
    const bf16* __restrict__ wt_hi, const bf16* __restrict__ wt_lo,
    const float* __restrict__ bq, const float* __restrict__ bk, const float* __restrict__ bv,
    bf16* __restrict__ q_hi, bf16* __restrict__ q_lo,
    bf16* __restrict__ k_hi, bf16* __restrict__ k_lo,
    bf16* __restrict__ v_hi, bf16* __restrict__ v_lo) {
    const int wz = blockIdx.z;
    const float* X = (wz == 0) ? qin : (wz == 1) ? kin : vin;
    const float* bias = (wz == 0) ? bq : (wz == 1) ? bk : bv;
    const bf16* wh = wt_hi + (size_t)wz * DMODEL * DMODEL;
    const bf16* wl = wt_lo + (size_t)wz * DMODEL * DMODEL;
    const int tid = threadIdx.x, wv = tid >> 6, lane = tid & 63, g = lane >> 4, c = lane & 15;
    const f32x4 z4 = {0.f, 0.f, 0.f, 0.f};
    f32x4 acc[4] = {z4, z4, z4, z4};

    if (wz < 2) {
        // A = X rows (m), B = W rows (n): out[m][n], coalesced q/k stores
        const int m0 = blockIdx.x * 64 + wv * 16;
        const int n0 = blockIdx.y * 64;
        for (int kk = 0; kk < DMODEL; kk += 32) {
            const float* xp = X + (size_t)(m0 + c) * DMODEL + kk + g * 8;
            float4 x0 = *(const float4*)xp;
            float4 x1 = *(const float4*)(xp + 4);
            float fv[8] = {x0.x, x0.y, x0.z, x0.w, x1.x, x1.y, x1.z, x1.w};
            bf16x8 ah, al;
#pragma unroll
            for (int i = 0; i < 8; i++) {
                bf16 hh, ll;
                split2(fv[i], hh, ll);
                ah[i] = hh;
                al[i] = ll;
            }
#pragma unroll
            for (int sub = 0; sub < 4; sub++) {
                const size_t wo = (size_t)(n0 + sub * 16 + c) * DMODEL + kk + g * 8;
                bf16x8 bh = *(const bf16x8*)(wh + wo);
                bf16x8 bl = *(const bf16x8*)(wl + wo);
                acc[sub] = mfma16(ah, bh, acc[sub]);
                acc[sub] = mfma16(ah, bl, acc[sub]);
                acc[sub] = mfma16(al, bh, acc[sub]);
            }
        }
#pragma unroll
        for (int sub = 0; sub < 4; sub++) {
            const int n = n0 + sub * 16 + c;
            const float bval = bias[n];
            const int hh = n >> 6, hd = n & 63;
#pragma unroll
            for (int r = 0; r < 4; r++) {
                const int m = m0 + g * 4 + r;
                const int bb = m >> 11, t = m & (SEQ - 1);
                float val = acc[sub][r] + bval;
                bf16 vh, vl;
                split2(val, vh, vl);
                const size_t o = ((size_t)((bb * NH + hh) * SEQ + t)) * HDIM + hd;
                if (wz == 0) { q_hi[o] = vh; q_lo[o] = vl; }
                else         { k_hi[o] = vh; k_lo[o] = vl; }
            }
        }
    } else {
        // V: A = Wt rows (hd), B = X rows (t): out[hd][t], coalesced transposed stores
        const int t0 = blockIdx.x * 64;
        const int hd0 = blockIdx.y * 64 + wv * 16;
        for (int kk = 0; kk < DMODEL; kk += 32) {
            const size_t wo = (size_t)(hd0 + c) * DMODEL + kk + g * 8;
            bf16x8 ah = *(const bf16x8*)(wh + wo);
            bf16x8 al = *(const bf16x8*)(wl + wo);
#pragma unroll
            for (int sub = 0; sub < 4; sub++) {
                const float* xp = X + (size_t)(t0 + sub * 16 + c) * DMODEL + kk + g * 8;
                float4 x0 = *(const float4*)xp;
                float4 x1 = *(const float4*)(xp + 4);
                float fv[8] = {x0.x, x0.y, x0.z, x0.w, x1.x, x1.y, x1.z, x1.w};
                bf16x8 bh, bl;
#pragma unroll
                for (int i = 0; i < 8; i++) {
                    bf16 hh, ll;
                    split2(fv[i], hh, ll);
                    bh[i] = hh;
                    bl[i] = ll;
                }
                acc[sub] = mfma16(ah, bh, acc[sub]);
                acc[sub] = mfma16(al, bh, acc[sub]);
                acc[sub] = mfma16(ah, bl, acc[sub]);
            }
        }
#pragma unroll
        for (int sub = 0; sub < 4; sub++) {
#pragma unroll
            for (int r = 0; r < 4; r++) {
                const int mg = t0 + sub * 16 + c;      // t global (over BSZ*SEQ)
                const int bb = mg >> 11, tt = mg & (SEQ - 1);
                const int ng = hd0 + g * 4 + r;        // model dim
                const int hh = ng >> 6, hdi = ng & 63;
                float val = acc[sub][r] + bias[ng];
                bf16 vh, vl;
                split2(val, vh, vl);
                const size_t o = ((size_t)((bb * NH + hh) * HDIM + hdi)) * SEQ + tt;
                v_hi[o] = vh;
                v_lo[o] = vl;
            }
        }
    }
}

// ---------------- K2: R[b,h,t,j] = q[t] . Er[j]  (GEMM, fp16 output, LDS-staged coalesced store) ----------------
__global__ __launch_bounds__(256) void rel_kernel(
    const bf16* __restrict__ q_hi, const bf16* __restrict__ q_lo,
    const bf16* __restrict__ er_hi, const bf16* __restrict__ er_lo,
    _Float16* __restrict__ R) {
    __shared__ _Float16 rst[4][16][72];
    const int bh = blockIdx.z;
    const int h = bh & 7;
    const int tid = threadIdx.x, wv = tid >> 6, lane = tid & 63, g = lane >> 4, c = lane & 15;
    const int t0 = blockIdx.x * 64 + wv * 16;
    const int j0 = blockIdx.y * 64;
    const bf16* qh = q_hi + (size_t)bh * SEQ * HDIM;
    const bf16* ql = q_lo + (size_t)bh * SEQ * HDIM;
    const bf16* eh = er_hi + (size_t)h * 2048 * HDIM;
    const bf16* el = er_lo + (size_t)h * 2048 * HDIM;
    const f32x4 z4 = {0.f, 0.f, 0.f, 0.f};
    f32x4 acc[4] = {z4, z4, z4, z4};
#pragma unroll
    for (int kc = 0; kc < 2; kc++) {
        const int kk = kc * 32 + g * 8;
        bf16x8 ah = *(const bf16x8*)(qh + (size_t)(t0 + c) * HDIM + kk);
        bf16x8 al = *(const bf16x8*)(ql + (size_t)(t0 + c) * HDIM + kk);
#pragma unroll
        for (int sub = 0; sub < 4; sub++) {
            bf16x8 bh_ = *(const bf16x8*)(eh + (size_t)(j0 + sub * 16 + c) * HDIM + kk);
            bf16x8 bl_ = *(const bf16x8*)(el + (size_t)(j0 + sub * 16 + c) * HDIM + kk);
            acc[sub] = mfma16(ah, bh_, acc[sub]);
            acc[sub] = mfma16(ah, bl_, acc[sub]);
            acc[sub] = mfma16(al, bh_, acc[sub]);
        }
    }
#pragma unroll
    for (int sub = 0; sub < 4; sub++)
#pragma unroll
        for (int r = 0; r < 4; r++)
            rst[wv][g * 4 + r][sub * 16 + c] = (_Float16)acc[sub][r];
    // wave-private LDS -> vectorized coalesced global store (16B per lane)
#pragma unroll
    for (int it = 0; it < 2; it++) {
        const int e = it * 512 + lane * 8;
        const int row = e >> 6, col = e & 63;
        float4 v = *(const float4*)&rst[wv][row][col];
        *(float4*)&R[((size_t)bh * SEQ + t0 + row) * RJS + j0 + col] = v;
    }
}

// ---------------- K3: fused attention ----------------
// Pass 1: logits = (QK^T + rel)*scale -> written raw into attn buffer; per-row online m,l.
// Pass 2: read logits back (coalesced), normalize -> attn, PV via MFMA. 4 waves split s-range.
__global__ __launch_bounds__(256) void attn_kernel(
    const bf16* __restrict__ q_hi, const bf16* __restrict__ q_lo,
    const bf16* __restrict__ k_hi, const bf16* __restrict__ k_lo,
    const bf16* __restrict__ v_hi, const bf16* __restrict__ v_lo,
    const _Float16* __restrict__ R, const int* __restrict__ layer_p,
    float* out, float* attn) {
    __shared__ __align__(16) char smem_raw[18048];
    float (*att_s)[16][36] = (float (*)[16][36])smem_raw;   // [4][16][36] per-wave, 9216 B
    float (*obuf)[16][68]  = (float (*)[16][68])smem_raw;   // [4][16][68], 17408 B (aliases att_s)
    float2* ml  = (float2*)(smem_raw + 17408);              // [4][16]
    float2* fml = (float2*)(smem_raw + 17920);              // [16]

    const int bh = blockIdx.y;
    const int b = bh >> 3, h = bh & 7;
    const int tid = threadIdx.x, wv = tid >> 6, lane = tid & 63, g = lane >> 4, c = lane & 15;
    const int t0 = blockIdx.x * 16;
    const int layer = layer_p[0];
    const int strd = 1 << layer;
    const int dil = min(1 + (SEQ - 1) / strd, MAXLEN);
    const int sq0 = wv * 512;   // this wave's s-range [sq0, sq0+512)

    const bf16* qh_p = q_hi + ((size_t)bh * SEQ + t0) * HDIM;
    const bf16* ql_p = q_lo + ((size_t)bh * SEQ + t0) * HDIM;
    const bf16* kh_p = k_hi + (size_t)bh * SEQ * HDIM;
    const bf16* kl_p = k_lo + (size_t)bh * SEQ * HDIM;
    const bf16* vh_p = v_hi + (size_t)bh * HDIM * SEQ;
    const bf16* vl_p = v_lo + (size_t)bh * HDIM * SEQ;
    const _Float16* Rp = R + (size_t)bh * SEQ * RJS;
    float* attn_p = attn + (size_t)bh * SEQ * SEQ;

    bf16x8 qh[2], ql[2];
#pragma unroll
    for (int kc = 0; kc < 2; kc++) {
        qh[kc] = *(const bf16x8*)(qh_p + c * HDIM + kc * 32 + g * 8);
        ql[kc] = *(const bf16x8*)(ql_p + c * HDIM + kc * 32 + g * 8);
    }

    // ---- pass 1: compute logits once, store raw, track online m/l ----
    float m_r[4], l_r[4];
#pragma unroll
    for (int r = 0; r < 4; r++) { m_r[r] = -1e30f; l_r[r] = 0.f; }

    for (int ti = 0; ti < 32; ti++) {
        const int s0 = sq0 + ti * 16;
        const f32x4 z = {0.f, 0.f, 0.f, 0.f};
        f32x4 aA = z, aB = z, aC = z;
#pragma unroll
        for (int kc = 0; kc < 2; kc++) {
            const size_t ko = (size_t)(s0 + c) * HDIM + kc * 32 + g * 8;
            bf16x8 kh8 = *(const bf16x8*)(kh_p + ko);
            bf16x8 kl8 = *(const bf16x8*)(kl_p + ko);
            aA = mfma16(qh[kc], kh8, aA);
            aB = mfma16(qh[kc], kl8, aB);
            aC = mfma16(ql[kc], kh8, aC);
        }
        f32x4 lg = aA + aB + aC;
#pragma unroll
        for (int r = 0; r < 4; r++) {
            const int t = t0 + g * 4 + r;
            const int dd = s0 + c - t;
            const int mm = dd >> layer;
            const bool ok = ((dd & (strd - 1)) == 0) & (mm > -dil) & (mm < dil);
            const int j = ok ? 1023 + mm : 2047;    // row 2047 of R is exactly 0 (Er padded)
            const float rel = (float)Rp[(size_t)t * RJS + j];
            const float x = (lg[r] + rel) * 0.125f;
            attn_p[(size_t)t * SEQ + s0 + c] = x;
            const float mn = fmaxf(m_r[r], x);
            l_r[r] = l_r[r] * __expf(m_r[r] - mn) + __expf(x - mn);
            m_r[r] = mn;
        }
    }
    // merge across 16 c-lanes
#pragma unroll
    for (int mask = 1; mask < 16; mask <<= 1) {
#pragma unroll
        for (int r = 0; r < 4; r++) {
            float om = __shfl_xor(m_r[r], mask);
            float ol = __shfl_xor(l_r[r], mask);
            float mn = fmaxf(m_r[r], om);
            l_r[r] = l_r[r] * __expf(m_r[r] - mn) + ol * __expf(om - mn);
            m_r[r] = mn;
        }
    }
    if (c == 0) {
#pragma unroll
        for (int r = 0; r < 4; r++) {
            float2 v; v.x = m_r[r]; v.y = l_r[r];
            ml[wv * 16 + g * 4 + r] = v;
        }
    }
    __syncthreads();
    if (tid < 16) {
        float m = -1e30f;
#pragma unroll
        for (int w = 0; w < 4; w++) m = fmaxf(m, ml[w * 16 + tid].x);
        float l = 0.f;
#pragma unroll
        for (int w = 0; w < 4; w++) l += ml[w * 16 + tid].y * __expf(ml[w * 16 + tid].x - m);
        float2 v; v.x = m; v.y = 1.f / l;
        fml[tid] = v;
    }
    __syncthreads();
    const int rw = lane >> 2;          // row this lane handles in pass-2 streaming
    const int cg = (lane & 3) * 8;     // col-group (8 floats)
    const float2 myml = fml[rw];

    // ---- pass 2: read logits back, normalize, write attn, PV ----
    const f32x4 z4 = {0.f, 0.f, 0.f, 0.f};
    f32x4 oacc[4] = {z4, z4, z4, z4};

    for (int ch = 0; ch < 16; ch++) {
        const int s0 = sq0 + ch * 32;
        float* ap = attn_p + (size_t)(t0 + rw) * SEQ + s0 + cg;
        float4 x0 = *(const float4*)ap;
        float4 x1 = *(const float4*)(ap + 4);
        float pvv[8] = {x0.x, x0.y, x0.z, x0.w, x1.x, x1.y, x1.z, x1.w};
#pragma unroll
        for (int i = 0; i < 8; i++) pvv[i] = __expf(pvv[i] - myml.x) * myml.y;
        float4 p0, p1;
        p0.x = pvv[0]; p0.y = pvv[1]; p0.z = pvv[2]; p0.w = pvv[3];
        p1.x = pvv[4]; p1.y = pvv[5]; p1.z = pvv[6]; p1.w = pvv[7];
        *(float4*)ap = p0;
        *(float4*)(ap + 4) = p1;
        *(float4*)&att_s[wv][rw][cg] = p0;
        *(float4*)&att_s[wv][rw][cg + 4] = p1;
        // rebuild P as MFMA A-fragments (hi/lo split) — wave-private LDS
        const float* fp = &att_s[wv][c][g * 8];
        float4 f0 = *(const float4*)fp;
        float4 f1 = *(const float4*)(fp + 4);
        float fv[8] = {f0.x, f0.y, f0.z, f0.w, f1.x, f1.y, f1.z, f1.w};
        bf16x8 pah, pal;
#pragma unroll
        for (int i = 0; i < 8; i++) {
            bf16 hh, ll;
            split2(fv[i], hh, ll);
            pah[i] = hh;
            pal[i] = ll;
        }
#pragma unroll
        for (int sub = 0; sub < 4; sub++) {
            const size_t vo = (size_t)(sub * 16 + c) * SEQ + s0 + g * 8;
            bf16x8 vh8 = *(const bf16x8*)(vh_p + vo);
            bf16x8 vl8 = *(const bf16x8*)(vl_p + vo);
            oacc[sub] = mfma16(pah, vh8, oacc[sub]);
            oacc[sub] = mfma16(pah, vl8, oacc[sub]);
            oacc[sub] = mfma16(pal, vh8, oacc[sub]);
        }
    }

    // ---- merge PV partials across the 4 waves ----
    __syncthreads();   // everyone done with att_s (obuf aliases it)
#pragma unroll
    for (int sub = 0; sub < 4; sub++)
#pragma unroll
        for (int r = 0; r < 4; r++)
            obuf[wv][g * 4 + r][sub * 16 + c] = oacc[sub][r];
    __syncthreads();
    {
        const int e = tid * 4;
        const int row = e >> 6, col = e & 63;
        float4 s = *(const float4*)&obuf[0][row][col];
        float4 s1 = *(const float4*)&obuf[1][row][col];
        float4 s2 = *(const float4*)&obuf[2][row][col];
        float4 s3 = *(const float4*)&obuf[3][row][col];
        s.x += s1.x + s2.x + s3.x;
        s.y += s1.y + s2.y + s3.y;
        s.z += s1.z + s2.z + s3.z;
        s.w += s1.w + s2.w + s3.w;
        *(float4*)&out[((size_t)b * SEQ + t0 + row) * DMODEL + h * HDIM + col] = s;
    }
}

extern "C" void kernel_launch(void* const* d_in, const int* in_sizes, int n_in,
                              void* d_out, int out_size, void* d_ws, size_t ws_size,
                              hipStream_t stream) {
    const float* query = (const float*)d_in[0];
    const float* key = (const float*)d_in[1];
    const float* value = (const float*)d_in[2];
    const float* Wq = (const float*)d_in[3];
    const float* bq = (const float*)d_in[4];
    const float* Wk = (const float*)d_in[5];
    const float* bk = (const float*)d_in[6];
    const float* Wv = (const float*)d_in[7];
    const float* bv = (const float*)d_in[8];
    const float* Er = (const float*)d_in[9];
    const int* layer = (const int*)d_in[10];

    char* ws = (char*)d_ws;
    size_t off = 0;
    bf16* wt_hi = (bf16*)(ws + off); off += (size_t)3 * DMODEL * DMODEL * 2;
    bf16* wt_lo = (bf16*)(ws + off); off += (size_t)3 * DMODEL * DMODEL * 2;
    bf16* er_hi = (bf16*)(ws + off); off += (size_t)NH * 2048 * HDIM * 2;
    bf16* er_lo = (bf16*)(ws + off); off += (size_t)NH * 2048 * HDIM * 2;
    bf16* q_hi = (bf16*)(ws + off); off += (size_t)BSZ * NH * SEQ * HDIM * 2;
    bf16* q_lo = (bf16*)(ws + off); off += (size_t)BSZ * NH * SEQ * HDIM * 2;
    bf16* k_hi = (bf16*)(ws + off); off += (size_t)BSZ * NH * SEQ * HDIM * 2;
    bf16* k_lo = (bf16*)(ws + off); off += (size_t)BSZ * NH * SEQ * HDIM * 2;
    bf16* v_hi = (bf16*)(ws + off); off += (size_t)BSZ * NH * SEQ * HDIM * 2;
    bf16* v_lo = (bf16*)(ws + off); off += (size_t)BSZ * NH * SEQ * HDIM * 2;
    _Float16* Rbuf = (_Float16*)(ws + off); off += (size_t)BSZ * NH * SEQ * RJS * 2;

    float* out = (float*)d_out;
    float* attn = out + OUT_ELEMS;

    prep_w<<<dim3(8, 8, 3), 256, 0, stream>>>(Wq, Wk, Wv, wt_hi, wt_lo);
    prep_er<<<(NH * 2048 * HDIM) / 256, 256, 0, stream>>>(Er, er_hi, er_lo);
    proj_kernel<<<dim3(64, 8, 3), 256, 0, stream>>>(query, key, value, wt_hi, wt_lo,
                                                    bq, bk, bv,
                                                    q_hi, q_lo, k_hi, k_lo, v_hi, v_lo);
    rel_kernel<<<dim3(32, 32, 16), 256, 0, stream>>>(q_hi, q_lo, er_hi, er_lo, Rbuf);
    attn_kernel<<<dim3(128, 16), 256, 0, stream>>>(q_hi, q_lo, k_hi, k_lo, v_hi, v_lo,
                                                   Rbuf, layer, out, attn);
}

// Round 4
// 844.814 us; speedup vs baseline: 1.3806x; 1.0641x over previous
//
#include <hip/hip_runtime.h>

#define BSZ 2
#define SEQ 2048
#define DMODEL 512
#define NH 8
#define HDIM 64
#define LROW 2047
#define RJS 2048
#define MAXLEN 1024
#define OUT_ELEMS (BSZ * SEQ * DMODEL)

typedef __bf16 bf16;
typedef bf16 bf16x8 __attribute__((ext_vector_type(8)));
typedef float f32x4 __attribute__((ext_vector_type(4)));

__device__ __forceinline__ f32x4 mfma16(bf16x8 a, bf16x8 b, f32x4 c) {
    return __builtin_amdgcn_mfma_f32_16x16x32_bf16(a, b, c, 0, 0, 0);
}
__device__ __forceinline__ void split2(float x, bf16 &h, bf16 &l) {
    h = (bf16)x;
    l = (bf16)(x - (float)h);
}
__device__ __forceinline__ unsigned pack_h2(float a, float b) {
    _Float16 ha = (_Float16)a, hb = (_Float16)b;
    unsigned short ua = __builtin_bit_cast(unsigned short, ha);
    unsigned short ub = __builtin_bit_cast(unsigned short, hb);
    return (unsigned)ua | ((unsigned)ub << 16);
}
__device__ __forceinline__ void unpack_h2(unsigned p, float &a, float &b) {
    unsigned short ua = (unsigned short)(p & 0xffff);
    unsigned short ub = (unsigned short)(p >> 16);
    a = (float)__builtin_bit_cast(_Float16, ua);
    b = (float)__builtin_bit_cast(_Float16, ub);
}

// ---------------- K0a: transpose + hi/lo split of Wq/Wk/Wv -> Wt[n][k] ----------------
__global__ __launch_bounds__(256) void prep_w(const float* __restrict__ Wq,
                                              const float* __restrict__ Wk,
                                              const float* __restrict__ Wv,
                                              bf16* __restrict__ wt_hi,
                                              bf16* __restrict__ wt_lo) {
    __shared__ float tile[64][65];
    const int wz = blockIdx.z;
    const float* W = (wz == 0) ? Wq : (wz == 1) ? Wk : Wv;
    bf16* oh = wt_hi + (size_t)wz * DMODEL * DMODEL;
    bf16* ol = wt_lo + (size_t)wz * DMODEL * DMODEL;
    const int k0 = blockIdx.x * 64;
    const int n0 = blockIdx.y * 64;
    const int tid = threadIdx.x;
    for (int e = tid; e < 64 * 64; e += 256) {
        int kk = e >> 6, nn = e & 63;
        tile[nn][kk] = W[(size_t)(k0 + kk) * DMODEL + n0 + nn];
    }
    __syncthreads();
    for (int e = tid; e < 64 * 64; e += 256) {
        int nn = e >> 6, kk = e & 63;
        float x = tile[nn][kk];
        bf16 h, l;
        split2(x, h, l);
        oh[(size_t)(n0 + nn) * DMODEL + k0 + kk] = h;
        ol[(size_t)(n0 + nn) * DMODEL + k0 + kk] = l;
    }
}

// ---------------- K0b: hi/lo split of Er -> [h][2048][64] (row 2047 zeroed) ----------------
__global__ __launch_bounds__(256) void prep_er(const float* __restrict__ Er,
                                               bf16* __restrict__ er_hi,
                                               bf16* __restrict__ er_lo) {
    const int idx = blockIdx.x * 256 + threadIdx.x;
    const int h = idx >> 17;
    const int rem = idx & 131071;
    const int j = rem >> 6, d = rem & 63;
    float x = (j < LROW) ? Er[((size_t)h * LROW + j) * HDIM + d] : 0.f;
    bf16 hh, ll;
    split2(x, hh, ll);
    er_hi[idx] = hh;
    er_lo[idx] = ll;
}

// ---------------- K1: q/k/v projections. q/k -> [b,h,t,hd]; v via swapped operands -> [b,h,hd,t] ----------------
__global__ __launch_bounds__(256) void proj_kernel(
    const float* __restrict__ qin, const float* __restrict__ kin, const float* __restrict__ vin,
    const bf16* __restrict__ wt_hi, const bf16* __restrict__ wt_lo,
    const float* __restrict__ bq, const float* __restrict__ bk, const float* __restrict__ bv,
    bf16* __restrict__ q_hi, bf16* __restrict__ q_lo,
    bf16* __restrict__ k_hi, bf16* __restrict__ k_lo,
    bf16* __restrict__ v_hi, bf16* __restrict__ v_lo) {
    const int wz = blockIdx.z;
    const float* X = (wz == 0) ? qin : (wz == 1) ? kin : vin;
    const float* bias = (wz == 0) ? bq : (wz == 1) ? bk : bv;
    const bf16* wh = wt_hi + (size_t)wz * DMODEL * DMODEL;
    const bf16* wl = wt_lo + (size_t)wz * DMODEL * DMODEL;
    const int tid = threadIdx.x, wv = tid >> 6, lane = tid & 63, g = lane >> 4, c = lane & 15;
    const f32x4 z4 = {0.f, 0.f, 0.f, 0.f};
    f32x4 acc[4] = {z4, z4, z4, z4};

    if (wz < 2) {
        const int m0 = blockIdx.x * 64 + wv * 16;
        const int n0 = blockIdx.y * 64;
        for (int kk = 0; kk < DMODEL; kk += 32) {
            const float* xp = X + (size_t)(m0 + c) * DMODEL + kk + g * 8;
            float4 x0 = *(const float4*)xp;
            float4 x1 = *(const float4*)(xp + 4);
            float fv[8] = {x0.x, x0.y, x0.z, x0.w, x1.x, x1.y, x1.z, x1.w};
            bf16x8 ah, al;
#pragma unroll
            for (int i = 0; i < 8; i++) {
                bf16 hh, ll;
                split2(fv[i], hh, ll);
                ah[i] = hh;
                al[i] = ll;
            }
#pragma unroll
            for (int sub = 0; sub < 4; sub++) {
                const size_t wo = (size_t)(n0 + sub * 16 + c) * DMODEL + kk + g * 8;
                bf16x8 bh = *(const bf16x8*)(wh + wo);
                bf16x8 bl = *(const bf16x8*)(wl + wo);
                acc[sub] = mfma16(ah, bh, acc[sub]);
                acc[sub] = mfma16(ah, bl, acc[sub]);
                acc[sub] = mfma16(al, bh, acc[sub]);
            }
        }
#pragma unroll
        for (int sub = 0; sub < 4; sub++) {
            const int n = n0 + sub * 16 + c;
            const float bval = bias[n];
            const int hh = n >> 6, hd = n & 63;
#pragma unroll
            for (int r = 0; r < 4; r++) {
                const int m = m0 + g * 4 + r;
                const int bb = m >> 11, t = m & (SEQ - 1);
                float val = acc[sub][r] + bval;
                bf16 vh, vl;
                split2(val, vh, vl);
                const size_t o = ((size_t)((bb * NH + hh) * SEQ + t)) * HDIM + hd;
                if (wz == 0) { q_hi[o] = vh; q_lo[o] = vl; }
                else         { k_hi[o] = vh; k_lo[o] = vl; }
            }
        }
    } else {
        const int t0 = blockIdx.x * 64;
        const int hd0 = blockIdx.y * 64 + wv * 16;
        for (int kk = 0; kk < DMODEL; kk += 32) {
            const size_t wo = (size_t)(hd0 + c) * DMODEL + kk + g * 8;
            bf16x8 ah = *(const bf16x8*)(wh + wo);
            bf16x8 al = *(const bf16x8*)(wl + wo);
#pragma unroll
            for (int sub = 0; sub < 4; sub++) {
                const float* xp = X + (size_t)(t0 + sub * 16 + c) * DMODEL + kk + g * 8;
                float4 x0 = *(const float4*)xp;
                float4 x1 = *(const float4*)(xp + 4);
                float fv[8] = {x0.x, x0.y, x0.z, x0.w, x1.x, x1.y, x1.z, x1.w};
                bf16x8 bh, bl;
#pragma unroll
                for (int i = 0; i < 8; i++) {
                    bf16 hh, ll;
                    split2(fv[i], hh, ll);
                    bh[i] = hh;
                    bl[i] = ll;
                }
                acc[sub] = mfma16(ah, bh, acc[sub]);
                acc[sub] = mfma16(al, bh, acc[sub]);
                acc[sub] = mfma16(ah, bl, acc[sub]);
            }
        }
#pragma unroll
        for (int sub = 0; sub < 4; sub++) {
#pragma unroll
            for (int r = 0; r < 4; r++) {
                const int mg = t0 + sub * 16 + c;
                const int bb = mg >> 11, tt = mg & (SEQ - 1);
                const int ng = hd0 + g * 4 + r;
                const int hh = ng >> 6, hdi = ng & 63;
                float val = acc[sub][r] + bias[ng];
                bf16 vh, vl;
                split2(val, vh, vl);
                const size_t o = ((size_t)((bb * NH + hh) * HDIM + hdi)) * SEQ + tt;
                v_hi[o] = vh;
                v_lo[o] = vl;
            }
        }
    }
}

// ---------------- K2: R[b,h,t,j] = q[t] . Er[j]  (GEMM, fp16 output, LDS-staged coalesced store) ----------------
__global__ __launch_bounds__(256) void rel_kernel(
    const bf16* __restrict__ q_hi, const bf16* __restrict__ q_lo,
    const bf16* __restrict__ er_hi, const bf16* __restrict__ er_lo,
    _Float16* __restrict__ R) {
    __shared__ _Float16 rst[4][16][72];
    const int bh = blockIdx.z;
    const int h = bh & 7;
    const int tid = threadIdx.x, wv = tid >> 6, lane = tid & 63, g = lane >> 4, c = lane & 15;
    const int t0 = blockIdx.x * 64 + wv * 16;
    const int j0 = blockIdx.y * 64;
    const bf16* qh = q_hi + (size_t)bh * SEQ * HDIM;
    const bf16* ql = q_lo + (size_t)bh * SEQ * HDIM;
    const bf16* eh = er_hi + (size_t)h * 2048 * HDIM;
    const bf16* el = er_lo + (size_t)h * 2048 * HDIM;
    const f32x4 z4 = {0.f, 0.f, 0.f, 0.f};
    f32x4 acc[4] = {z4, z4, z4, z4};
#pragma unroll
    for (int kc = 0; kc < 2; kc++) {
        const int kk = kc * 32 + g * 8;
        bf16x8 ah = *(const bf16x8*)(qh + (size_t)(t0 + c) * HDIM + kk);
        bf16x8 al = *(const bf16x8*)(ql + (size_t)(t0 + c) * HDIM + kk);
#pragma unroll
        for (int sub = 0; sub < 4; sub++) {
            bf16x8 bh_ = *(const bf16x8*)(eh + (size_t)(j0 + sub * 16 + c) * HDIM + kk);
            bf16x8 bl_ = *(const bf16x8*)(el + (size_t)(j0 + sub * 16 + c) * HDIM + kk);
            acc[sub] = mfma16(ah, bh_, acc[sub]);
            acc[sub] = mfma16(ah, bl_, acc[sub]);
            acc[sub] = mfma16(al, bh_, acc[sub]);
        }
    }
#pragma unroll
    for (int sub = 0; sub < 4; sub++)
#pragma unroll
        for (int r = 0; r < 4; r++)
            rst[wv][g * 4 + r][sub * 16 + c] = (_Float16)acc[sub][r];
#pragma unroll
    for (int it = 0; it < 2; it++) {
        const int e = it * 512 + lane * 8;
        const int row = e >> 6, col = e & 63;
        float4 v = *(const float4*)&rst[wv][row][col];
        *(float4*)&R[((size_t)bh * SEQ + t0 + row) * RJS + j0 + col] = v;
    }
}

// ---------------- K3: fused attention, SINGLE pass over logits ----------------
// 8 waves x 256-col strips. P~ = exp(logit-4) kept as packed fp16 in registers;
// l accumulated in f32; after block merge, probs written once + PV, out scaled.
__global__ __launch_bounds__(512) void attn_kernel(
    const bf16* __restrict__ q_hi, const bf16* __restrict__ q_lo,
    const bf16* __restrict__ k_hi, const bf16* __restrict__ k_lo,
    const bf16* __restrict__ v_hi, const bf16* __restrict__ v_lo,
    const _Float16* __restrict__ R, const int* __restrict__ layer_p,
    float* out, float* attn) {
    __shared__ __align__(16) char smem_raw[35456];
    float (*att_s)[16][36] = (float (*)[16][36])smem_raw;   // [8][16][36] = 18432 B
    float (*obuf)[16][68]  = (float (*)[16][68])smem_raw;   // [8][16][68] = 34816 B (aliases att_s)
    float* ml  = (float*)(smem_raw + 34816);                // [8][16]
    float* fml = (float*)(smem_raw + 35328);                // [16] inv_l

    const int bh = blockIdx.y;
    const int b = bh >> 3, h = bh & 7;
    const int tid = threadIdx.x, wv = tid >> 6, lane = tid & 63, g = lane >> 4, c = lane & 15;
    const int t0 = blockIdx.x * 16;
    const int layer = layer_p[0];
    const int strd = 1 << layer;
    const int dil = min(1 + (SEQ - 1) / strd, MAXLEN);
    const int sq0 = wv * 256;   // this wave's s-strip [sq0, sq0+256)

    const bf16* qh_p = q_hi + ((size_t)bh * SEQ + t0) * HDIM;
    const bf16* ql_p = q_lo + ((size_t)bh * SEQ + t0) * HDIM;
    const bf16* kh_p = k_hi + (size_t)bh * SEQ * HDIM;
    const bf16* kl_p = k_lo + (size_t)bh * SEQ * HDIM;
    const bf16* vh_p = v_hi + (size_t)bh * HDIM * SEQ;
    const bf16* vl_p = v_lo + (size_t)bh * HDIM * SEQ;
    const _Float16* Rp = R + (size_t)bh * SEQ * RJS;
    float* attn_p = attn + (size_t)bh * SEQ * SEQ;

    bf16x8 qh[2], ql[2];
#pragma unroll
    for (int kc = 0; kc < 2; kc++) {
        qh[kc] = *(const bf16x8*)(qh_p + c * HDIM + kc * 32 + g * 8);
        ql[kc] = *(const bf16x8*)(ql_p + c * HDIM + kc * 32 + g * 8);
    }

    // ---- single logits pass: P~ = exp(x-4) into registers, l in f32 ----
    unsigned pA[16], pB[16];        // per tile: rows (0,1) and (2,3) packed fp16
    float l_r[4] = {0.f, 0.f, 0.f, 0.f};

#pragma unroll
    for (int ti = 0; ti < 16; ti++) {
        const int s0 = sq0 + ti * 16;
        const f32x4 z = {0.f, 0.f, 0.f, 0.f};
        f32x4 aA = z, aB = z, aC = z;
#pragma unroll
        for (int kc = 0; kc < 2; kc++) {
            const size_t ko = (size_t)(s0 + c) * HDIM + kc * 32 + g * 8;
            bf16x8 kh8 = *(const bf16x8*)(kh_p + ko);
            bf16x8 kl8 = *(const bf16x8*)(kl_p + ko);
            aA = mfma16(qh[kc], kh8, aA);
            aB = mfma16(qh[kc], kl8, aB);
            aC = mfma16(ql[kc], kh8, aC);
        }
        f32x4 lg = aA + aB + aC;
        float e[4];
#pragma unroll
        for (int r = 0; r < 4; r++) {
            const int t = t0 + g * 4 + r;
            const int dd = s0 + c - t;
            const int mm = dd >> layer;
            const bool ok = ((dd & (strd - 1)) == 0) & (mm > -dil) & (mm < dil);
            const int j = ok ? 1023 + mm : 2047;    // R row j=2047 is exactly 0
            const float rel = (float)Rp[(size_t)t * RJS + j];
            const float x = (lg[r] + rel) * 0.125f - 4.0f;   // offset keeps exp in fp16 range
            e[r] = __expf(x);
            l_r[r] += e[r];
        }
        pA[ti] = pack_h2(e[0], e[1]);
        pB[ti] = pack_h2(e[2], e[3]);
    }
    // merge l across 16 c-lanes of each group
#pragma unroll
    for (int mask = 1; mask < 16; mask <<= 1)
#pragma unroll
        for (int r = 0; r < 4; r++) l_r[r] += __shfl_xor(l_r[r], mask);
    if (c == 0) {
#pragma unroll
        for (int r = 0; r < 4; r++) ml[wv * 16 + g * 4 + r] = l_r[r];
    }
    __syncthreads();
    if (tid < 16) {
        float l = 0.f;
#pragma unroll
        for (int w = 0; w < 8; w++) l += ml[w * 16 + tid];
        fml[tid] = 1.f / l;
    }
    __syncthreads();
    float inv_l[4];
#pragma unroll
    for (int r = 0; r < 4; r++) inv_l[r] = fml[g * 4 + r];

    // ---- output phase: normalize in-register, write probs once, PV ----
    const f32x4 z4 = {0.f, 0.f, 0.f, 0.f};
    f32x4 oacc[4] = {z4, z4, z4, z4};
    const int rw = lane >> 2;
    const int cg = (lane & 3) * 8;

#pragma unroll
    for (int ch = 0; ch < 8; ch++) {
#pragma unroll
        for (int half = 0; half < 2; half++) {
            const int ti = ch * 2 + half;
            float e0, e1, e2, e3;
            unpack_h2(pA[ti], e0, e1);
            unpack_h2(pB[ti], e2, e3);
            att_s[wv][g * 4 + 0][half * 16 + c] = e0 * inv_l[0];
            att_s[wv][g * 4 + 1][half * 16 + c] = e1 * inv_l[1];
            att_s[wv][g * 4 + 2][half * 16 + c] = e2 * inv_l[2];
            att_s[wv][g * 4 + 3][half * 16 + c] = e3 * inv_l[3];
        }
        const int s0 = sq0 + ch * 32;
        // coalesced probs store (128B per 4 lanes)
        {
            const float* ap = &att_s[wv][rw][cg];
            float4 p0 = *(const float4*)ap;
            float4 p1 = *(const float4*)(ap + 4);
            float* gp = attn_p + (size_t)(t0 + rw) * SEQ + s0 + cg;
            *(float4*)gp = p0;
            *(float4*)(gp + 4) = p1;
        }
        // A-fragment rebuild (hi/lo split) for PV
        const float* fp = &att_s[wv][c][g * 8];
        float4 f0 = *(const float4*)fp;
        float4 f1 = *(const float4*)(fp + 4);
        float fv[8] = {f0.x, f0.y, f0.z, f0.w, f1.x, f1.y, f1.z, f1.w};
        bf16x8 pah, pal;
#pragma unroll
        for (int i = 0; i < 8; i++) {
            bf16 hh, ll;
            split2(fv[i], hh, ll);
            pah[i] = hh;
            pal[i] = ll;
        }
#pragma unroll
        for (int sub = 0; sub < 4; sub++) {
            const size_t vo = (size_t)(sub * 16 + c) * SEQ + s0 + g * 8;
            bf16x8 vh8 = *(const bf16x8*)(vh_p + vo);
            bf16x8 vl8 = *(const bf16x8*)(vl_p + vo);
            oacc[sub] = mfma16(pah, vh8, oacc[sub]);
            oacc[sub] = mfma16(pah, vl8, oacc[sub]);
            oacc[sub] = mfma16(pal, vh8, oacc[sub]);
        }
    }

    // ---- merge PV partials across the 8 waves ----
    __syncthreads();   // att_s dead; obuf aliases it
#pragma unroll
    for (int sub = 0; sub < 4; sub++)
#pragma unroll
        for (int r = 0; r < 4; r++)
            obuf[wv][g * 4 + r][sub * 16 + c] = oacc[sub][r];
    __syncthreads();
    if (tid < 256) {
        const int e = tid * 4;
        const int row = e >> 6, col = e & 63;
        float4 s = *(const float4*)&obuf[0][row][col];
#pragma unroll
        for (int w = 1; w < 8; w++) {
            float4 sw = *(const float4*)&obuf[w][row][col];
            s.x += sw.x; s.y += sw.y; s.z += sw.z; s.w += sw.w;
        }
        *(float4*)&out[((size_t)b * SEQ + t0 + row) * DMODEL + h * HDIM + col] = s;
    }
}

extern "C" void kernel_launch(void* const* d_in, const int* in_sizes, int n_in,
                              void* d_out, int out_size, void* d_ws, size_t ws_size,
                              hipStream_t stream) {
    const float* query = (const float*)d_in[0];
    const float* key = (const float*)d_in[1];
    const float* value = (const float*)d_in[2];
    const float* Wq = (const float*)d_in[3];
    const float* bq = (const float*)d_in[4];
    const float* Wk = (const float*)d_in[5];
    const float* bk = (const float*)d_in[6];
    const float* Wv = (const float*)d_in[7];
    const float* bv = (const float*)d_in[8];
    const float* Er = (const float*)d_in[9];
    const int* layer = (const int*)d_in[10];

    char* ws = (char*)d_ws;
    size_t off = 0;
    bf16* wt_hi = (bf16*)(ws + off); off += (size_t)3 * DMODEL * DMODEL * 2;
    bf16* wt_lo = (bf16*)(ws + off); off += (size_t)3 * DMODEL * DMODEL * 2;
    bf16* er_hi = (bf16*)(ws + off); off += (size_t)NH * 2048 * HDIM * 2;
    bf16* er_lo = (bf16*)(ws + off); off += (size_t)NH * 2048 * HDIM * 2;
    bf16* q_hi = (bf16*)(ws + off); off += (size_t)BSZ * NH * SEQ * HDIM * 2;
    bf16* q_lo = (bf16*)(ws + off); off += (size_t)BSZ * NH * SEQ * HDIM * 2;
    bf16* k_hi = (bf16*)(ws + off); off += (size_t)BSZ * NH * SEQ * HDIM * 2;
    bf16* k_lo = (bf16*)(ws + off); off += (size_t)BSZ * NH * SEQ * HDIM * 2;
    bf16* v_hi = (bf16*)(ws + off); off += (size_t)BSZ * NH * SEQ * HDIM * 2;
    bf16* v_lo = (bf16*)(ws + off); off += (size_t)BSZ * NH * SEQ * HDIM * 2;
    _Float16* Rbuf = (_Float16*)(ws + off); off += (size_t)BSZ * NH * SEQ * RJS * 2;

    float* out = (float*)d_out;
    float* attn = out + OUT_ELEMS;

    prep_w<<<dim3(8, 8, 3), 256, 0, stream>>>(Wq, Wk, Wv, wt_hi, wt_lo);
    prep_er<<<(NH * 2048 * HDIM) / 256, 256, 0, stream>>>(Er, er_hi, er_lo);
    proj_kernel<<<dim3(64, 8, 3), 256, 0, stream>>>(query, key, value, wt_hi, wt_lo,
                                                    bq, bk, bv,
                                                    q_hi, q_lo, k_hi, k_lo, v_hi, v_lo);
    rel_kernel<<<dim3(32, 32, 16), 256, 0, stream>>>(q_hi, q_lo, er_hi, er_lo, Rbuf);
    attn_kernel<<<dim3(128, 16), 512, 0, stream>>>(q_hi, q_lo, k_hi, k_lo, v_hi, v_lo,
                                                   Rbuf, layer, out, attn);
}

// Round 5
// 823.168 us; speedup vs baseline: 1.4169x; 1.0263x over previous
//
#include <hip/hip_runtime.h>

#define BSZ 2
#define SEQ 2048
#define DMODEL 512
#define NH 8
#define HDIM 64
#define LROW 2047
#define RJS 2048
#define MAXLEN 1024
#define OUT_ELEMS (BSZ * SEQ * DMODEL)

typedef __bf16 bf16;
typedef bf16 bf16x8 __attribute__((ext_vector_type(8)));
typedef float f32x4 __attribute__((ext_vector_type(4)));

__device__ __forceinline__ f32x4 mfma16(bf16x8 a, bf16x8 b, f32x4 c) {
    return __builtin_amdgcn_mfma_f32_16x16x32_bf16(a, b, c, 0, 0, 0);
}
__device__ __forceinline__ void split2(float x, bf16 &h, bf16 &l) {
    h = (bf16)x;
    l = (bf16)(x - (float)h);
}

// ---------------- K0a: transpose + hi/lo split of Wq/Wk/Wv -> Wt[n][k] ----------------
__global__ __launch_bounds__(256) void prep_w(const float* __restrict__ Wq,
                                              const float* __restrict__ Wk,
                                              const float* __restrict__ Wv,
                                              bf16* __restrict__ wt_hi,
                                              bf16* __restrict__ wt_lo) {
    __shared__ float tile[64][65];
    const int wz = blockIdx.z;
    const float* W = (wz == 0) ? Wq : (wz == 1) ? Wk : Wv;
    bf16* oh = wt_hi + (size_t)wz * DMODEL * DMODEL;
    bf16* ol = wt_lo + (size_t)wz * DMODEL * DMODEL;
    const int k0 = blockIdx.x * 64;
    const int n0 = blockIdx.y * 64;
    const int tid = threadIdx.x;
    for (int e = tid; e < 64 * 64; e += 256) {
        int kk = e >> 6, nn = e & 63;
        tile[nn][kk] = W[(size_t)(k0 + kk) * DMODEL + n0 + nn];
    }
    __syncthreads();
    for (int e = tid; e < 64 * 64; e += 256) {
        int nn = e >> 6, kk = e & 63;
        float x = tile[nn][kk];
        bf16 h, l;
        split2(x, h, l);
        oh[(size_t)(n0 + nn) * DMODEL + k0 + kk] = h;
        ol[(size_t)(n0 + nn) * DMODEL + k0 + kk] = l;
    }
}

// ---------------- K0b: hi/lo split of Er -> [h][2048][64] (row 2047 zeroed) ----------------
__global__ __launch_bounds__(256) void prep_er(const float* __restrict__ Er,
                                               bf16* __restrict__ er_hi,
                                               bf16* __restrict__ er_lo) {
    const int idx = blockIdx.x * 256 + threadIdx.x;
    const int h = idx >> 17;
    const int rem = idx & 131071;
    const int j = rem >> 6, d = rem & 63;
    float x = (j < LROW) ? Er[((size_t)h * LROW + j) * HDIM + d] : 0.f;
    bf16 hh, ll;
    split2(x, hh, ll);
    er_hi[idx] = hh;
    er_lo[idx] = ll;
}

// ---------------- K1: q/k/v projections. q/k -> [b,h,t,hd]; v via swapped operands -> [b,h,hd,t] ----------------
__global__ __launch_bounds__(256) void proj_kernel(
    const float* __restrict__ qin, const float* __restrict__ kin, const float* __restrict__ vin,
    const bf16* __restrict__ wt_hi, const bf16* __restrict__ wt_lo,
    const float* __restrict__ bq, const float* __restrict__ bk, const float* __restrict__ bv,
    bf16* __restrict__ q_hi, bf16* __restrict__ q_lo,
    bf16* __restrict__ k_hi, bf16* __restrict__ k_lo,
    bf16* __restrict__ v_hi, bf16* __restrict__ v_lo) {
    const int wz = blockIdx.z;
    const float* X = (wz == 0) ? qin : (wz == 1) ? kin : vin;
    const float* bias = (wz == 0) ? bq : (wz == 1) ? bk : bv;
    const bf16* wh = wt_hi + (size_t)wz * DMODEL * DMODEL;
    const bf16* wl = wt_lo + (size_t)wz * DMODEL * DMODEL;
    const int tid = threadIdx.x, wv = tid >> 6, lane = tid & 63, g = lane >> 4, c = lane & 15;
    const f32x4 z4 = {0.f, 0.f, 0.f, 0.f};
    f32x4 acc[4] = {z4, z4, z4, z4};

    if (wz < 2) {
        const int m0 = blockIdx.x * 64 + wv * 16;
        const int n0 = blockIdx.y * 64;
        for (int kk = 0; kk < DMODEL; kk += 32) {
            const float* xp = X + (size_t)(m0 + c) * DMODEL + kk + g * 8;
            float4 x0 = *(const float4*)xp;
            float4 x1 = *(const float4*)(xp + 4);
            float fv[8] = {x0.x, x0.y, x0.z, x0.w, x1.x, x1.y, x1.z, x1.w};
            bf16x8 ah, al;
#pragma unroll
            for (int i = 0; i < 8; i++) {
                bf16 hh, ll;
                split2(fv[i], hh, ll);
                ah[i] = hh;
                al[i] = ll;
            }
#pragma unroll
            for (int sub = 0; sub < 4; sub++) {
                const size_t wo = (size_t)(n0 + sub * 16 + c) * DMODEL + kk + g * 8;
                bf16x8 bh = *(const bf16x8*)(wh + wo);
                bf16x8 bl = *(const bf16x8*)(wl + wo);
                acc[sub] = mfma16(ah, bh, acc[sub]);
                acc[sub] = mfma16(ah, bl, acc[sub]);
                acc[sub] = mfma16(al, bh, acc[sub]);
            }
        }
#pragma unroll
        for (int sub = 0; sub < 4; sub++) {
            const int n = n0 + sub * 16 + c;
            const float bval = bias[n];
            const int hh = n >> 6, hd = n & 63;
#pragma unroll
            for (int r = 0; r < 4; r++) {
                const int m = m0 + g * 4 + r;
                const int bb = m >> 11, t = m & (SEQ - 1);
                float val = acc[sub][r] + bval;
                bf16 vh, vl;
                split2(val, vh, vl);
                const size_t o = ((size_t)((bb * NH + hh) * SEQ + t)) * HDIM + hd;
                if (wz == 0) { q_hi[o] = vh; q_lo[o] = vl; }
                else         { k_hi[o] = vh; k_lo[o] = vl; }
            }
        }
    } else {
        const int t0 = blockIdx.x * 64;
        const int hd0 = blockIdx.y * 64 + wv * 16;
        for (int kk = 0; kk < DMODEL; kk += 32) {
            const size_t wo = (size_t)(hd0 + c) * DMODEL + kk + g * 8;
            bf16x8 ah = *(const bf16x8*)(wh + wo);
            bf16x8 al = *(const bf16x8*)(wl + wo);
#pragma unroll
            for (int sub = 0; sub < 4; sub++) {
                const float* xp = X + (size_t)(t0 + sub * 16 + c) * DMODEL + kk + g * 8;
                float4 x0 = *(const float4*)xp;
                float4 x1 = *(const float4*)(xp + 4);
                float fv[8] = {x0.x, x0.y, x0.z, x0.w, x1.x, x1.y, x1.z, x1.w};
                bf16x8 bh, bl;
#pragma unroll
                for (int i = 0; i < 8; i++) {
                    bf16 hh, ll;
                    split2(fv[i], hh, ll);
                    bh[i] = hh;
                    bl[i] = ll;
                }
                acc[sub] = mfma16(ah, bh, acc[sub]);
                acc[sub] = mfma16(al, bh, acc[sub]);
                acc[sub] = mfma16(ah, bl, acc[sub]);
            }
        }
#pragma unroll
        for (int sub = 0; sub < 4; sub++) {
#pragma unroll
            for (int r = 0; r < 4; r++) {
                const int mg = t0 + sub * 16 + c;
                const int bb = mg >> 11, tt = mg & (SEQ - 1);
                const int ng = hd0 + g * 4 + r;
                const int hh = ng >> 6, hdi = ng & 63;
                float val = acc[sub][r] + bias[ng];
                bf16 vh, vl;
                split2(val, vh, vl);
                const size_t o = ((size_t)((bb * NH + hh) * HDIM + hdi)) * SEQ + tt;
                v_hi[o] = vh;
                v_lo[o] = vl;
            }
        }
    }
}

// ---------------- K2: R[b,h,t,j] = q[t] . Er[j]  (GEMM, fp16 output, LDS-staged coalesced store) ----------------
__global__ __launch_bounds__(256) void rel_kernel(
    const bf16* __restrict__ q_hi, const bf16* __restrict__ q_lo,
    const bf16* __restrict__ er_hi, const bf16* __restrict__ er_lo,
    _Float16* __restrict__ R) {
    __shared__ _Float16 rst[4][16][72];
    const int bh = blockIdx.z;
    const int h = bh & 7;
    const int tid = threadIdx.x, wv = tid >> 6, lane = tid & 63, g = lane >> 4, c = lane & 15;
    const int t0 = blockIdx.x * 64 + wv * 16;
    const int j0 = blockIdx.y * 64;
    const bf16* qh = q_hi + (size_t)bh * SEQ * HDIM;
    const bf16* ql = q_lo + (size_t)bh * SEQ * HDIM;
    const bf16* eh = er_hi + (size_t)h * 2048 * HDIM;
    const bf16* el = er_lo + (size_t)h * 2048 * HDIM;
    const f32x4 z4 = {0.f, 0.f, 0.f, 0.f};
    f32x4 acc[4] = {z4, z4, z4, z4};
#pragma unroll
    for (int kc = 0; kc < 2; kc++) {
        const int kk = kc * 32 + g * 8;
        bf16x8 ah = *(const bf16x8*)(qh + (size_t)(t0 + c) * HDIM + kk);
        bf16x8 al = *(const bf16x8*)(ql + (size_t)(t0 + c) * HDIM + kk);
#pragma unroll
        for (int sub = 0; sub < 4; sub++) {
            bf16x8 bh_ = *(const bf16x8*)(eh + (size_t)(j0 + sub * 16 + c) * HDIM + kk);
            bf16x8 bl_ = *(const bf16x8*)(el + (size_t)(j0 + sub * 16 + c) * HDIM + kk);
            acc[sub] = mfma16(ah, bh_, acc[sub]);
            acc[sub] = mfma16(ah, bl_, acc[sub]);
            acc[sub] = mfma16(al, bh_, acc[sub]);
        }
    }
#pragma unroll
    for (int sub = 0; sub < 4; sub++)
#pragma unroll
        for (int r = 0; r < 4; r++)
            rst[wv][g * 4 + r][sub * 16 + c] = (_Float16)acc[sub][r];
#pragma unroll
    for (int it = 0; it < 2; it++) {
        const int e = it * 512 + lane * 8;
        const int row = e >> 6, col = e & 63;
        float4 v = *(const float4*)&rst[wv][row][col];
        *(float4*)&R[((size_t)bh * SEQ + t0 + row) * RJS + j0 + col] = v;
    }
}

// ---------------- K3: fused attention, single logits pass, P~ in LDS (fp16) ----------------
// 8 waves x 256-col strips. P~ = exp(logit-4) -> fp16 LDS; l in f32 regs; after
// block merge: probs written once (normalized), PV on unnormalized P~, oacc scaled.
#define PROW 264   // fp16 elems per P-row (256 + 8 pad, keeps 16B row alignment)
__global__ __launch_bounds__(512) void attn_kernel(
    const bf16* __restrict__ q_hi, const bf16* __restrict__ q_lo,
    const bf16* __restrict__ k_hi, const bf16* __restrict__ k_lo,
    const bf16* __restrict__ v_hi, const bf16* __restrict__ v_lo,
    const _Float16* __restrict__ R, const int* __restrict__ layer_p,
    float* out, float* attn) {
    __shared__ __align__(16) char smem_raw[68160];
    _Float16 (*pbuf)[16][PROW] = (_Float16 (*)[16][PROW])smem_raw;  // [8][16][264] = 67584 B
    float (*obuf)[16][68] = (float (*)[16][68])smem_raw;            // 34816 B, aliases pbuf (used after)
    float* ml  = (float*)(smem_raw + 67584);                        // [8][16]
    float* fml = (float*)(smem_raw + 68096);                        // [16] inv_l

    const int bh = blockIdx.y;
    const int b = bh >> 3, h = bh & 7;
    const int tid = threadIdx.x, wv = tid >> 6, lane = tid & 63, g = lane >> 4, c = lane & 15;
    const int t0 = blockIdx.x * 16;
    const int layer = layer_p[0];
    const int strd = 1 << layer;
    const int dil = min(1 + (SEQ - 1) / strd, MAXLEN);
    const int sq0 = wv * 256;   // this wave's s-strip [sq0, sq0+256)

    const bf16* qh_p = q_hi + ((size_t)bh * SEQ + t0) * HDIM;
    const bf16* ql_p = q_lo + ((size_t)bh * SEQ + t0) * HDIM;
    const bf16* kh_p = k_hi + (size_t)bh * SEQ * HDIM;
    const bf16* kl_p = k_lo + (size_t)bh * SEQ * HDIM;
    const bf16* vh_p = v_hi + (size_t)bh * HDIM * SEQ;
    const bf16* vl_p = v_lo + (size_t)bh * HDIM * SEQ;
    const _Float16* Rp = R + (size_t)bh * SEQ * RJS;
    float* attn_p = attn + (size_t)bh * SEQ * SEQ;

    bf16x8 qh[2], ql[2];
#pragma unroll
    for (int kc = 0; kc < 2; kc++) {
        qh[kc] = *(const bf16x8*)(qh_p + c * HDIM + kc * 32 + g * 8);
        ql[kc] = *(const bf16x8*)(ql_p + c * HDIM + kc * 32 + g * 8);
    }

    // ---- single logits pass: P~ = exp(x-4) -> LDS fp16, l in f32 ----
    float l_r[4] = {0.f, 0.f, 0.f, 0.f};

#pragma unroll
    for (int ti = 0; ti < 16; ti++) {
        const int s0 = sq0 + ti * 16;
        const f32x4 z = {0.f, 0.f, 0.f, 0.f};
        f32x4 aA = z, aB = z, aC = z;
#pragma unroll
        for (int kc = 0; kc < 2; kc++) {
            const size_t ko = (size_t)(s0 + c) * HDIM + kc * 32 + g * 8;
            bf16x8 kh8 = *(const bf16x8*)(kh_p + ko);
            bf16x8 kl8 = *(const bf16x8*)(kl_p + ko);
            aA = mfma16(qh[kc], kh8, aA);
            aB = mfma16(qh[kc], kl8, aB);
            aC = mfma16(ql[kc], kh8, aC);
        }
        f32x4 lg = aA + aB + aC;
#pragma unroll
        for (int r = 0; r < 4; r++) {
            const int t = t0 + g * 4 + r;
            const int dd = s0 + c - t;
            const int mm = dd >> layer;
            const bool ok = ((dd & (strd - 1)) == 0) & (mm > -dil) & (mm < dil);
            const int j = ok ? 1023 + mm : 2047;    // R row j=2047 is exactly 0
            const float rel = (float)Rp[(size_t)t * RJS + j];
            const float x = (lg[r] + rel) * 0.125f - 4.0f;   // offset keeps exp in fp16 range
            const float e = __expf(x);
            l_r[r] += e;
            pbuf[wv][g * 4 + r][ti * 16 + c] = (_Float16)e;
        }
    }
    // merge l across 16 c-lanes of each group
#pragma unroll
    for (int mask = 1; mask < 16; mask <<= 1)
#pragma unroll
        for (int r = 0; r < 4; r++) l_r[r] += __shfl_xor(l_r[r], mask);
    if (c == 0) {
#pragma unroll
        for (int r = 0; r < 4; r++) ml[wv * 16 + g * 4 + r] = l_r[r];
    }
    __syncthreads();
    if (tid < 16) {
        float l = 0.f;
#pragma unroll
        for (int w = 0; w < 8; w++) l += ml[w * 16 + tid];
        fml[tid] = 1.f / l;
    }
    __syncthreads();
    float inv_l[4];
#pragma unroll
    for (int r = 0; r < 4; r++) inv_l[r] = fml[g * 4 + r];

    // ---- output phase: write normalized probs, PV on unnormalized P~ ----
    const f32x4 z4 = {0.f, 0.f, 0.f, 0.f};
    f32x4 oacc[4] = {z4, z4, z4, z4};
    const int rw = lane >> 2;            // row for probs streaming
    const int cg = (lane & 3) * 8;       // col-group (8 fp16)
    const float myinv = fml[rw];

#pragma unroll
    for (int ch = 0; ch < 8; ch++) {
        const int s0 = sq0 + ch * 32;
        // normalized probs -> global (each quad covers one row's 32 cols)
        {
            _Float16 pv16[8];
            *(float4*)pv16 = *(const float4*)&pbuf[wv][rw][ch * 32 + cg];
            float4 p0, p1;
            p0.x = (float)pv16[0] * myinv; p0.y = (float)pv16[1] * myinv;
            p0.z = (float)pv16[2] * myinv; p0.w = (float)pv16[3] * myinv;
            p1.x = (float)pv16[4] * myinv; p1.y = (float)pv16[5] * myinv;
            p1.z = (float)pv16[6] * myinv; p1.w = (float)pv16[7] * myinv;
            float* gp = attn_p + (size_t)(t0 + rw) * SEQ + s0 + cg;
            *(float4*)gp = p0;
            *(float4*)(gp + 4) = p1;
        }
        // A-fragment (hi/lo split of unnormalized P~) for PV
        _Float16 pf16[8];
        *(float4*)pf16 = *(const float4*)&pbuf[wv][c][ch * 32 + g * 8];
        bf16x8 pah, pal;
#pragma unroll
        for (int i = 0; i < 8; i++) {
            bf16 hh, ll;
            split2((float)pf16[i], hh, ll);
            pah[i] = hh;
            pal[i] = ll;
        }
#pragma unroll
        for (int sub = 0; sub < 4; sub++) {
            const size_t vo = (size_t)(sub * 16 + c) * SEQ + s0 + g * 8;
            bf16x8 vh8 = *(const bf16x8*)(vh_p + vo);
            bf16x8 vl8 = *(const bf16x8*)(vl_p + vo);
            oacc[sub] = mfma16(pah, vh8, oacc[sub]);
            oacc[sub] = mfma16(pah, vl8, oacc[sub]);
            oacc[sub] = mfma16(pal, vh8, oacc[sub]);
        }
    }
    // scale by inv_l (PV ran on unnormalized P~)
#pragma unroll
    for (int sub = 0; sub < 4; sub++)
#pragma unroll
        for (int r = 0; r < 4; r++) oacc[sub][r] *= inv_l[r];

    // ---- merge PV partials across the 8 waves ----
    __syncthreads();   // pbuf dead; obuf aliases it
#pragma unroll
    for (int sub = 0; sub < 4; sub++)
#pragma unroll
        for (int r = 0; r < 4; r++)
            obuf[wv][g * 4 + r][sub * 16 + c] = oacc[sub][r];
    __syncthreads();
    if (tid < 256) {
        const int e = tid * 4;
        const int row = e >> 6, col = e & 63;
        float4 s = *(const float4*)&obuf[0][row][col];
#pragma unroll
        for (int w = 1; w < 8; w++) {
            float4 sw = *(const float4*)&obuf[w][row][col];
            s.x += sw.x; s.y += sw.y; s.z += sw.z; s.w += sw.w;
        }
        *(float4*)&out[((size_t)b * SEQ + t0 + row) * DMODEL + h * HDIM + col] = s;
    }
}

extern "C" void kernel_launch(void* const* d_in, const int* in_sizes, int n_in,
                              void* d_out, int out_size, void* d_ws, size_t ws_size,
                              hipStream_t stream) {
    const float* query = (const float*)d_in[0];
    const float* key = (const float*)d_in[1];
    const float* value = (const float*)d_in[2];
    const float* Wq = (const float*)d_in[3];
    const float* bq = (const float*)d_in[4];
    const float* Wk = (const float*)d_in[5];
    const float* bk = (const float*)d_in[6];
    const float* Wv = (const float*)d_in[7];
    const float* bv = (const float*)d_in[8];
    const float* Er = (const float*)d_in[9];
    const int* layer = (const int*)d_in[10];

    char* ws = (char*)d_ws;
    size_t off = 0;
    bf16* wt_hi = (bf16*)(ws + off); off += (size_t)3 * DMODEL * DMODEL * 2;
    bf16* wt_lo = (bf16*)(ws + off); off += (size_t)3 * DMODEL * DMODEL * 2;
    bf16* er_hi = (bf16*)(ws + off); off += (size_t)NH * 2048 * HDIM * 2;
    bf16* er_lo = (bf16*)(ws + off); off += (size_t)NH * 2048 * HDIM * 2;
    bf16* q_hi = (bf16*)(ws + off); off += (size_t)BSZ * NH * SEQ * HDIM * 2;
    bf16* q_lo = (bf16*)(ws + off); off += (size_t)BSZ * NH * SEQ * HDIM * 2;
    bf16* k_hi = (bf16*)(ws + off); off += (size_t)BSZ * NH * SEQ * HDIM * 2;
    bf16* k_lo = (bf16*)(ws + off); off += (size_t)BSZ * NH * SEQ * HDIM * 2;
    bf16* v_hi = (bf16*)(ws + off); off += (size_t)BSZ * NH * SEQ * HDIM * 2;
    bf16* v_lo = (bf16*)(ws + off); off += (size_t)BSZ * NH * SEQ * HDIM * 2;
    _Float16* Rbuf = (_Float16*)(ws + off); off += (size_t)BSZ * NH * SEQ * RJS * 2;

    float* out = (float*)d_out;
    float* attn = out + OUT_ELEMS;

    prep_w<<<dim3(8, 8, 3), 256, 0, stream>>>(Wq, Wk, Wv, wt_hi, wt_lo);
    prep_er<<<(NH * 2048 * HDIM) / 256, 256, 0, stream>>>(Er, er_hi, er_lo);
    proj_kernel<<<dim3(64, 8, 3), 256, 0, stream>>>(query, key, value, wt_hi, wt_lo,
                                                    bq, bk, bv,
                                                    q_hi, q_lo, k_hi, k_lo, v_hi, v_lo);
    rel_kernel<<<dim3(32, 32, 16), 256, 0, stream>>>(q_hi, q_lo, er_hi, er_lo, Rbuf);
    attn_kernel<<<dim3(128, 16), 512, 0, stream>>>(q_hi, q_lo, k_hi, k_lo, v_hi, v_lo,
                                                   Rbuf, layer, out, attn);
}